// Round 9
// baseline (50.061 us; speedup 1.0000x reference)
//
#include <hip/hip_runtime.h>
#include <hip/hip_fp16.h>
#include <math.h>

typedef float vf4 __attribute__((ext_vector_type(4)));
typedef unsigned int u32;

#define LN_EPS 1e-5f
#define NBINS  1024          // LUT nodes over diamond-angle v in [-1,3)
#define NLUT   (NBINS + 2)   // +2 duplicate tail entries: wrap-free lerp & iu=1024 safety

// ============================================================================
// R8 identity (verified, absmax 0.0156): LN(3) output has ONE dof (a circle);
// softmax weights w(theta) depend only on the direction of
//   (P,Q) = (sqrt3*(x1-x0), 2*x2-x0-x1).
// R9 refinements:
//  - weights sum to 1 -> store only (w0,w1); out = x2 + w0(x0-x2) + w1(x1-x2)
//    (exact for lerped nodes: lerp preserves the sum).
//  - (w0,w1) packed f16x2 in one u32 -> 2-node lerp fetch = lut[iu],lut[iu+1]
//    adjacent dwords = ONE ds_read2_b32 (was 6 ds_read_b32). f16 error
//    <=5e-4/w -> output err <~0.01; budget 0.016+0.01 << 0.066.
//  - explicit 1-deep prefetch in the grid-stride loop (uniform 8 iters/thread).
// ============================================================================

__global__ void nn2_lut_setup(const float* __restrict__ lnw, const float* __restrict__ lnb,
                              const float* __restrict__ w1,  const float* __restrict__ b1,
                              const float* __restrict__ w2,  const float* __restrict__ b2,
                              u32* __restrict__ ws)
{
    int i = blockIdx.x * blockDim.x + threadIdx.x;
    if (i >= NLUT) return;
    int node = i & (NBINS - 1);                 // entries 1024,1025 duplicate nodes 0,1
    // invert diamond angle: v -> (P,Q) with |P|+|Q|=1
    float v  = (float)node * (4.0f / NBINS) - 1.0f;
    float dd = (v <= 1.0f) ? v : (2.0f - v);
    float Pm = 1.0f - fabsf(dd);
    float P  = (v <= 1.0f) ? Pm : -Pm;
    float Q  = dd;
    // direction -> point on the LN circle (radius sqrt(3))
    float n = rsqrtf(P * P + Q * Q);
    float p = 1.7320508075688772f * P * n;
    float q = 1.7320508075688772f * Q * n;
    const float is2 = 0.7071067811865476f;      // 1/sqrt2
    const float is6 = 0.4082482904638631f;      // 1/sqrt6
    float t0 =  p * is2 + q * is6;
    float t1 = -p * is2 + q * is6;
    float t2 = -2.0f * q * is6;
    // exact LN-affine -> MLP -> softmax at this node
    float h0 = t0 * lnw[0] + lnb[0];
    float h1 = t1 * lnw[1] + lnb[1];
    float h2 = t2 * lnw[2] + lnb[2];
    float l0 = b2[0], l1 = b2[1], l2 = b2[2];
    for (int j = 0; j < 16; ++j) {
        float a = fmaf(w1[3*j], h0, fmaf(w1[3*j+1], h1, fmaf(w1[3*j+2], h2, b1[j])));
        a = fmaxf(a, 0.0f);
        l0 = fmaf(w2[j],    a, l0);
        l1 = fmaf(w2[16+j], a, l1);
        l2 = fmaf(w2[32+j], a, l2);
    }
    float m  = fmaxf(l0, fmaxf(l1, l2));
    float e0 = expf(l0 - m), e1 = expf(l1 - m), e2 = expf(l2 - m);
    float r  = 1.0f / (e0 + e1 + e2);
    float W0 = e0 * r, W1 = e1 * r;             // W2 = 1 - W0 - W1 implicit
    u32 pk = ((u32)__half_as_ushort(__float2half_rn(W1)) << 16)
           |  (u32)__half_as_ushort(__float2half_rn(W0));
    ws[i] = pk;
}

__device__ __forceinline__ float row_out(float x0, float x1, float x2,
                                         const u32* lut)
{
    float P   = (x1 - x0) * 1.7320508075688772f;
    float Q   = fmaf(2.0f, x2, -(x0 + x1));
    float den = fabsf(P) + fabsf(Q) + 1e-20f;
    float dd  = Q * __builtin_amdgcn_rcpf(den);
    float v   = (P >= 0.0f) ? dd : (2.0f - dd);
    float u   = fmaf(v, 256.0f, 256.0f);        // [0,1024] (+tiny rcp slop)
    int   iu  = (int)u;
    iu = iu < 0 ? 0 : (iu > NBINS ? NBINS : iu);   // med3 clamp -> reads <= NLUT-1
    float f   = u - (float)iu;
    u32 n0 = lut[iu];
    u32 n1 = lut[iu + 1];                       // adjacent dword -> ds_read2_b32
    float a0 = __half2float(__ushort_as_half((unsigned short)(n0 & 0xffffu)));
    float a1 = __half2float(__ushort_as_half((unsigned short)(n0 >> 16)));
    float b0 = __half2float(__ushort_as_half((unsigned short)(n1 & 0xffffu)));
    float b1 = __half2float(__ushort_as_half((unsigned short)(n1 >> 16)));
    float w0 = fmaf(f, b0 - a0, a0);
    float w1 = fmaf(f, b1 - a1, a1);
    return fmaf(w0, x0 - x2, fmaf(w1, x1 - x2, x2));
}

__global__ __launch_bounds__(256) void nn2_lut_main(
    const float* __restrict__ x, const u32* __restrict__ ws,
    float* __restrict__ out, long long nrows, long long T, long long stride)
{
    __shared__ u32 lut[NLUT];                   // 4.1 KB
    int tid = threadIdx.x;
    for (int k = tid; k < NLUT; k += 256) lut[k] = ws[k];
    __syncthreads();

    const vf4* x4  = reinterpret_cast<const vf4*>(x);
    vf4*       out4 = reinterpret_cast<vf4*>(out);

    long long grp = (long long)blockIdx.x * 256 + tid;
    if (grp >= T) return;

    // prefetch current group (3x dwordx4 = 48B contiguous per thread)
    vf4 va, vb, vc;
    bool full = (grp * 4 + 4 <= nrows);
    if (full) { va = x4[grp*3]; vb = x4[grp*3 + 1]; vc = x4[grp*3 + 2]; }

    while (true) {
        // issue NEXT group's loads before computing current (hide HBM latency)
        long long nxt = grp + stride;
        bool nhas = (nxt < T);
        bool nfull = false;
        vf4 na, nb, nc;
        if (nhas) {
            nfull = (nxt * 4 + 4 <= nrows);
            if (nfull) { na = x4[nxt*3]; nb = x4[nxt*3 + 1]; nc = x4[nxt*3 + 2]; }
        }

        if (full) {
            vf4 o;
            o.x = row_out(va.x, va.y, va.z, lut);
            o.y = row_out(va.w, vb.x, vb.y, lut);
            o.z = row_out(vb.z, vb.w, vc.x, lut);
            o.w = row_out(vc.y, vc.z, vc.w, lut);
            __builtin_nontemporal_store(o, &out4[grp]);
        } else {
            for (long long r = grp * 4; r < nrows; ++r)
                out[r] = row_out(x[r*3], x[r*3 + 1], x[r*3 + 2], lut);
        }

        if (!nhas) break;
        grp = nxt; full = nfull; va = na; vb = nb; vc = nc;
    }
}

// Fallback (ws too small): exact self-contained path (R7-proven).
__global__ __launch_bounds__(256) void nn2_fallback(
    const float* __restrict__ x,
    const float* __restrict__ lnw_g, const float* __restrict__ lnb_g,
    const float* __restrict__ w1_g,  const float* __restrict__ b1_g,
    const float* __restrict__ w2_g,  const float* __restrict__ b2_g,
    float* __restrict__ out, int nrows)
{
    int g = blockIdx.x * blockDim.x + threadIdx.x;
    long long base = (long long)g * 4;
    if (base >= nrows) return;
    const float lw0 = lnw_g[0], lw1 = lnw_g[1], lw2 = lnw_g[2];
    const float lb0 = lnb_g[0], lb1 = lnb_g[1], lb2 = lnb_g[2];
    float X[4][3];
    if (base + 4 <= nrows) {
        const float4* x4 = reinterpret_cast<const float4*>(x) + (long long)g * 3;
        float4 va = x4[0], vb = x4[1], vc = x4[2];
        X[0][0]=va.x; X[0][1]=va.y; X[0][2]=va.z;
        X[1][0]=va.w; X[1][1]=vb.x; X[1][2]=vb.y;
        X[2][0]=vb.z; X[2][1]=vb.w; X[2][2]=vc.x;
        X[3][0]=vc.y; X[3][1]=vc.z; X[3][2]=vc.w;
    } else {
        for (int r = 0; r < 4; ++r) {
            long long rr = (base + r < nrows) ? base + r : (long long)nrows - 1;
            X[r][0]=x[rr*3]; X[r][1]=x[rr*3+1]; X[r][2]=x[rr*3+2];
        }
    }
    float H[4][3];
#pragma unroll
    for (int r = 0; r < 4; ++r) {
        float x0=X[r][0], x1=X[r][1], x2=X[r][2];
        float mu=(x0+x1+x2)*(1.0f/3.0f);
        float d0=mu-x0, d1=mu-x1, d2=mu-x2;
        float rs=__builtin_amdgcn_rsqf(fmaf(fmaf(d0,d0,fmaf(d1,d1,d2*d2)),1.0f/3.0f,LN_EPS));
        H[r][0]=fmaf(d0*rs,lw0,lb0); H[r][1]=fmaf(d1*rs,lw1,lb1); H[r][2]=fmaf(d2*rs,lw2,lb2);
    }
    float L[4][3];
    { const float b20=b2_g[0],b21=b2_g[1],b22=b2_g[2];
#pragma unroll
      for (int r=0;r<4;++r){L[r][0]=b20;L[r][1]=b21;L[r][2]=b22;} }
#pragma unroll
    for (int j = 0; j < 16; ++j) {
        const float a0=w1_g[3*j],a1=w1_g[3*j+1],a2=w1_g[3*j+2],bj=b1_g[j];
        const float u0=w2_g[j],u1=w2_g[16+j],u2=w2_g[32+j];
#pragma unroll
        for (int r=0;r<4;++r){
            float hj=fmaf(H[r][2],a2,fmaf(H[r][1],a1,fmaf(H[r][0],a0,bj)));
            hj=fmaxf(hj,0.0f);
            L[r][0]=fmaf(hj,u0,L[r][0]); L[r][1]=fmaf(hj,u1,L[r][1]); L[r][2]=fmaf(hj,u2,L[r][2]);
        }
    }
    float O[4];
#pragma unroll
    for (int r=0;r<4;++r){
        float l0=L[r][0],l1=L[r][1],l2=L[r][2];
        float lm=fmaxf(l0,fmaxf(l1,l2));
        float s0=__expf(l0-lm),s1=__expf(l1-lm),s2=__expf(l2-lm);
        float rc=__builtin_amdgcn_rcpf(s0+s1+s2);
        O[r]=fmaf(X[r][0],s0,fmaf(X[r][1],s1,X[r][2]*s2))*rc;
    }
    if (base + 4 <= nrows) {
        float4 o; o.x=O[0];o.y=O[1];o.z=O[2];o.w=O[3];
        reinterpret_cast<float4*>(out)[g] = o;
    } else {
        for (int r = 0; r < 4 && base + r < nrows; ++r) out[base + r] = O[r];
    }
}

extern "C" void kernel_launch(void* const* d_in, const int* in_sizes, int n_in,
                              void* d_out, int out_size, void* d_ws, size_t ws_size,
                              hipStream_t stream) {
    const float* x    = (const float*)d_in[0];
    const float* lnw  = (const float*)d_in[1];
    const float* lnb  = (const float*)d_in[2];
    const float* w1   = (const float*)d_in[3];
    const float* b1   = (const float*)d_in[4];
    const float* w2   = (const float*)d_in[5];
    const float* b2   = (const float*)d_in[6];
    // d_in[7] (log_tau): softmin cancels exactly inside LayerNorm -> unused.
    float* out = (float*)d_out;
    long long nrows = out_size;

    if (ws_size >= (size_t)NLUT * sizeof(u32)) {
        u32* ws = (u32*)d_ws;
        nn2_lut_setup<<<(NLUT + 255) / 256, 256, 0, stream>>>(lnw, lnb, w1, b1, w2, b2, ws);
        long long T = (nrows + 3) / 4;
        long long need = (T + 255) / 256;
        int grid = (need < 2048) ? (int)need : 2048;   // 8 blocks/CU at full grid
        long long stride = (long long)grid * 256;
        nn2_lut_main<<<grid, 256, 0, stream>>>(x, ws, out, nrows, T, stride);
    } else {
        long long ngroups = (nrows + 3) / 4;
        int grid = (int)((ngroups + 255) / 256);
        nn2_fallback<<<grid, 256, 0, stream>>>(x, lnw, lnb, w1, b1, w2, b2, out, (int)nrows);
    }
}

// Round 10
// 47.765 us; speedup vs baseline: 1.0481x; 1.0481x over previous
//
#include <hip/hip_runtime.h>
#include <hip/hip_fp16.h>
#include <math.h>

typedef float vf4 __attribute__((ext_vector_type(4)));
typedef unsigned int u32;

#define LN_EPS 1e-5f
#define NBINS  1024          // LUT nodes over diamond-angle v in [-1,3)
#define NLUT   (NBINS + 2)   // +2 dup tail entries: wrap-free lerp, iu=1024 safety

// ============================================================================
// Identity (R8/R9-verified, absmax 0.0156): softmin cancels in LayerNorm;
// LN(3) output has ONE dof; softmax weights depend only on the direction of
// (P,Q) = (sqrt3*(x1-x0), 2*x2-x0-x1). Weights sum to 1 -> store (w0,w1) as
// f16x2; out = x2 + w0*(x0-x2) + w1*(x1-x2).
//
// R10 changes (targeting the 15% gap to the copy ceiling):
//  1. UNIT-STRIDE global reads: block stages 12KB/tile to LDS with lane-linear
//     dwordx4 (48 lines/3KB vs 144 for the old stride-48 pattern), threads
//     read their 48B AoS slice back from LDS (bank-offset math: 12t mod 32
//     covers all 32 banks once per 8-lane class -> conflict-free b128).
//  2. NO setup kernel: every block builds the 1026-entry LUT inline (~4
//     nodes/thread, overlapped with tile-0 prefetch). Single launch, no d_ws.
// ============================================================================

__device__ __forceinline__ u32 lut_entry(int node,
    const float* __restrict__ lnw, const float* __restrict__ lnb,
    const float* __restrict__ w1,  const float* __restrict__ b1,
    const float* __restrict__ w2,  const float* __restrict__ b2)
{
    // invert diamond angle: v -> (P,Q) with |P|+|Q|=1
    float v  = (float)node * (4.0f / NBINS) - 1.0f;
    float dd = (v <= 1.0f) ? v : (2.0f - v);
    float Pm = 1.0f - fabsf(dd);
    float P  = (v <= 1.0f) ? Pm : -Pm;
    float Q  = dd;
    // direction -> point on the LN circle (radius sqrt(3))
    float n = rsqrtf(P * P + Q * Q);
    float p = 1.7320508075688772f * P * n;
    float q = 1.7320508075688772f * Q * n;
    const float is2 = 0.7071067811865476f;   // 1/sqrt2
    const float is6 = 0.4082482904638631f;   // 1/sqrt6
    float t0 =  p * is2 + q * is6;
    float t1 = -p * is2 + q * is6;
    float t2 = -2.0f * q * is6;
    // exact LN-affine -> MLP -> softmax at this node (uniform s_loads, L2-hot)
    float h0 = t0 * lnw[0] + lnb[0];
    float h1 = t1 * lnw[1] + lnb[1];
    float h2 = t2 * lnw[2] + lnb[2];
    float l0 = b2[0], l1 = b2[1], l2 = b2[2];
    for (int j = 0; j < 16; ++j) {
        float a = fmaf(w1[3*j], h0, fmaf(w1[3*j+1], h1, fmaf(w1[3*j+2], h2, b1[j])));
        a = fmaxf(a, 0.0f);
        l0 = fmaf(w2[j],    a, l0);
        l1 = fmaf(w2[16+j], a, l1);
        l2 = fmaf(w2[32+j], a, l2);
    }
    float m  = fmaxf(l0, fmaxf(l1, l2));
    float e0 = expf(l0 - m), e1 = expf(l1 - m), e2 = expf(l2 - m);
    float r  = 1.0f / (e0 + e1 + e2);
    float W0 = e0 * r, W1 = e1 * r;          // W2 = 1 - W0 - W1 implicit
    return ((u32)__half_as_ushort(__float2half_rn(W1)) << 16)
         |  (u32)__half_as_ushort(__float2half_rn(W0));
}

__device__ __forceinline__ float row_out(float x0, float x1, float x2,
                                         const u32* lut)
{
    float P   = (x1 - x0) * 1.7320508075688772f;
    float Q   = fmaf(2.0f, x2, -(x0 + x1));
    float den = fabsf(P) + fabsf(Q) + 1e-20f;
    float dd  = Q * __builtin_amdgcn_rcpf(den);
    float v   = (P >= 0.0f) ? dd : (2.0f - dd);
    float u   = fmaf(v, 256.0f, 256.0f);        // [0,1024]
    int   iu  = (int)u;
    iu = iu < 0 ? 0 : (iu > NBINS ? NBINS : iu);
    float f   = u - (float)iu;
    u32 n0 = lut[iu];
    u32 n1 = lut[iu + 1];                       // adjacent dword -> ds_read2_b32
    float a0 = __half2float(__ushort_as_half((unsigned short)(n0 & 0xffffu)));
    float a1 = __half2float(__ushort_as_half((unsigned short)(n0 >> 16)));
    float b0 = __half2float(__ushort_as_half((unsigned short)(n1 & 0xffffu)));
    float b1 = __half2float(__ushort_as_half((unsigned short)(n1 >> 16)));
    float w0 = fmaf(f, b0 - a0, a0);
    float w1 = fmaf(f, b1 - a1, a1);
    return fmaf(w0, x0 - x2, fmaf(w1, x1 - x2, x2));
}

__global__ __launch_bounds__(256) void nn2_fused(
    const float* __restrict__ x,
    const float* __restrict__ lnw, const float* __restrict__ lnb,
    const float* __restrict__ w1,  const float* __restrict__ b1,
    const float* __restrict__ w2,  const float* __restrict__ b2,
    float* __restrict__ out, long long nrows, long long ntiles)
{
    __shared__ u32 lut[NLUT];                    // 4.1 KB
    __shared__ vf4 stage[768];                   // 12 KB: 256 groups x 48B
    const int tid = threadIdx.x;

    const vf4* x4   = reinterpret_cast<const vf4*>(x);
    vf4*       out4 = reinterpret_cast<vf4*>(out);

    // prefetch tile 0 (unit-stride dwordx4: lane i -> x4[base+i])
    long long tile = blockIdx.x;
    vf4 r0, r1, r2;
    bool pfull = false;
    if (tile < ntiles) {
        long long gb = tile * 256;
        pfull = ((gb + 256) * 4 <= nrows);
        if (pfull) {
            long long fb = gb * 3;
            r0 = x4[fb + tid];
            r1 = x4[fb + tid + 256];
            r2 = x4[fb + tid + 512];
        }
    }

    // build LUT inline (overlaps the loads above; ~4 nodes/thread)
    for (int i = tid; i < NLUT; i += 256)
        lut[i] = lut_entry(i & (NBINS - 1), lnw, lnb, w1, b1, w2, b2);

    for (; tile < ntiles; tile += gridDim.x) {
        long long gb = tile * 256;
        bool full = pfull;
        __syncthreads();                         // LUT ready / prev stage reads done
        if (full) {
            stage[tid]       = r0;
            stage[tid + 256] = r1;
            stage[tid + 512] = r2;
        }
        // prefetch next tile while staging/computing current
        long long ntile = tile + gridDim.x;
        pfull = false;
        if (ntile < ntiles) {
            long long ngb = ntile * 256;
            pfull = ((ngb + 256) * 4 <= nrows);
            if (pfull) {
                long long fb = ngb * 3;
                r0 = x4[fb + tid];
                r1 = x4[fb + tid + 256];
                r2 = x4[fb + tid + 512];
            }
        }
        __syncthreads();                         // stage ready
        if (full) {
            const vf4* my = &stage[3 * tid];     // 48B AoS slice, conflict-free b128
            vf4 va = my[0], vb = my[1], vc = my[2];
            vf4 o;
            o.x = row_out(va.x, va.y, va.z, lut);
            o.y = row_out(va.w, vb.x, vb.y, lut);
            o.z = row_out(vb.z, vb.w, vc.x, lut);
            o.w = row_out(vc.y, vc.z, vc.w, lut);
            __builtin_nontemporal_store(o, &out4[gb + tid]);
        } else {
            // partial tail tile: direct per-row path (block-uniform branch)
            long long grp = gb + tid;
            long long rbeg = grp * 4;
            for (long long r = rbeg; r < nrows && r < rbeg + 4; ++r)
                out[r] = row_out(x[r*3], x[r*3 + 1], x[r*3 + 2], lut);
        }
    }
}

extern "C" void kernel_launch(void* const* d_in, const int* in_sizes, int n_in,
                              void* d_out, int out_size, void* d_ws, size_t ws_size,
                              hipStream_t stream) {
    const float* x   = (const float*)d_in[0];
    const float* lnw = (const float*)d_in[1];
    const float* lnb = (const float*)d_in[2];
    const float* w1  = (const float*)d_in[3];
    const float* b1  = (const float*)d_in[4];
    const float* w2  = (const float*)d_in[5];
    const float* b2  = (const float*)d_in[6];
    // d_in[7] (log_tau): softmin cancels exactly inside LayerNorm -> unused.
    float* out = (float*)d_out;
    long long nrows = out_size;

    long long T      = (nrows + 3) / 4;          // 4-row groups
    long long ntiles = (T + 255) / 256;          // 256 groups (12KB) per tile
    int grid = (ntiles < 2048) ? (int)ntiles : 2048;

    nn2_fused<<<grid, 256, 0, stream>>>(x, lnw, lnb, w1, b1, w2, b2,
                                        out, nrows, ntiles);
}

// Round 11
// 47.635 us; speedup vs baseline: 1.0509x; 1.0027x over previous
//
#include <hip/hip_runtime.h>
#include <hip/hip_fp16.h>
#include <math.h>

typedef float vf4 __attribute__((ext_vector_type(4)));
typedef unsigned int u32;

#define LN_EPS 1e-5f
#define NBINS  1024          // LUT nodes over diamond-angle v in [-1,3)
#define NLUT   (NBINS + 2)   // +2 dup tail entries: wrap-free lerp, iu=1024 safety

// ============================================================================
// Identity (R8/R9-verified, absmax 0.0156): softmin cancels in LayerNorm;
// LN(3) output has ONE dof; softmax weights depend only on the direction of
// (P,Q) = (sqrt3*(x1-x0), 2*x2-x0-x1). Weights sum to 1 -> store (w0,w1) as
// f16x2; out = x2 + w0*(x0-x2) + w1*(x1-x2).
//
// R11 change: ZERO per-iteration barriers. R10's __syncthreads compiles to
// s_waitcnt vmcnt(0)+s_barrier, which drained the next-tile prefetch loads
// every iteration (they were issued between bar1 and bar2). Fix: WAVE-LOCAL
// LDS staging — wave w writes only stage[192w..192w+192) (unit-stride
// ds_write_b128) and thread (w,lane) reads stage[192w+3*lane..] — all reads
// are same-wave, and the per-wave DS pipe is in-order, so no barrier is
// needed. Only one barrier remains (after the inline LUT build). The 1-deep
// register prefetch now truly spans the compute phase.
// ============================================================================

__device__ __forceinline__ u32 lut_entry(int node,
    const float* __restrict__ lnw, const float* __restrict__ lnb,
    const float* __restrict__ w1,  const float* __restrict__ b1,
    const float* __restrict__ w2,  const float* __restrict__ b2)
{
    // invert diamond angle: v -> (P,Q) with |P|+|Q|=1
    float v  = (float)node * (4.0f / NBINS) - 1.0f;
    float dd = (v <= 1.0f) ? v : (2.0f - v);
    float Pm = 1.0f - fabsf(dd);
    float P  = (v <= 1.0f) ? Pm : -Pm;
    float Q  = dd;
    // direction -> point on the LN circle (radius sqrt(3))
    float n = rsqrtf(P * P + Q * Q);
    float p = 1.7320508075688772f * P * n;
    float q = 1.7320508075688772f * Q * n;
    const float is2 = 0.7071067811865476f;   // 1/sqrt2
    const float is6 = 0.4082482904638631f;   // 1/sqrt6
    float t0 =  p * is2 + q * is6;
    float t1 = -p * is2 + q * is6;
    float t2 = -2.0f * q * is6;
    // exact LN-affine -> MLP -> softmax at this node (uniform s_loads, L2-hot)
    float h0 = t0 * lnw[0] + lnb[0];
    float h1 = t1 * lnw[1] + lnb[1];
    float h2 = t2 * lnw[2] + lnb[2];
    float l0 = b2[0], l1 = b2[1], l2 = b2[2];
    for (int j = 0; j < 16; ++j) {
        float a = fmaf(w1[3*j], h0, fmaf(w1[3*j+1], h1, fmaf(w1[3*j+2], h2, b1[j])));
        a = fmaxf(a, 0.0f);
        l0 = fmaf(w2[j],    a, l0);
        l1 = fmaf(w2[16+j], a, l1);
        l2 = fmaf(w2[32+j], a, l2);
    }
    float m  = fmaxf(l0, fmaxf(l1, l2));
    float e0 = expf(l0 - m), e1 = expf(l1 - m), e2 = expf(l2 - m);
    float r  = 1.0f / (e0 + e1 + e2);
    float W0 = e0 * r, W1 = e1 * r;          // W2 = 1 - W0 - W1 implicit
    return ((u32)__half_as_ushort(__float2half_rn(W1)) << 16)
         |  (u32)__half_as_ushort(__float2half_rn(W0));
}

__device__ __forceinline__ float row_out(float x0, float x1, float x2,
                                         const u32* lut)
{
    float P   = (x1 - x0) * 1.7320508075688772f;
    float Q   = fmaf(2.0f, x2, -(x0 + x1));
    float den = fabsf(P) + fabsf(Q) + 1e-20f;
    float dd  = Q * __builtin_amdgcn_rcpf(den);
    float v   = (P >= 0.0f) ? dd : (2.0f - dd);
    float u   = fmaf(v, 256.0f, 256.0f);        // [0,1024]
    int   iu  = (int)u;
    iu = iu < 0 ? 0 : (iu > NBINS ? NBINS : iu);
    float f   = u - (float)iu;
    u32 n0 = lut[iu];
    u32 n1 = lut[iu + 1];                       // adjacent dword -> ds_read2_b32
    float a0 = __half2float(__ushort_as_half((unsigned short)(n0 & 0xffffu)));
    float a1 = __half2float(__ushort_as_half((unsigned short)(n0 >> 16)));
    float b0 = __half2float(__ushort_as_half((unsigned short)(n1 & 0xffffu)));
    float b1 = __half2float(__ushort_as_half((unsigned short)(n1 >> 16)));
    float w0 = fmaf(f, b0 - a0, a0);
    float w1 = fmaf(f, b1 - a1, a1);
    return fmaf(w0, x0 - x2, fmaf(w1, x1 - x2, x2));
}

__global__ __launch_bounds__(256) void nn2_fused(
    const float* __restrict__ x,
    const float* __restrict__ lnw, const float* __restrict__ lnb,
    const float* __restrict__ w1,  const float* __restrict__ b1,
    const float* __restrict__ w2,  const float* __restrict__ b2,
    float* __restrict__ out, long long nrows, long long ntiles)
{
    __shared__ u32 lut[NLUT];                    // 4.1 KB
    __shared__ vf4 stage[768];                   // 12 KB; wave w owns [192w,192w+192)
    const int tid  = threadIdx.x;
    const int wave = tid >> 6;
    const int lane = tid & 63;
    const int wbase = wave * 192;                // vf4 units

    const vf4* x4   = reinterpret_cast<const vf4*>(x);
    vf4*       out4 = reinterpret_cast<vf4*>(out);

    // prefetch tile 0 (unit-stride within the wave's 3KB slice)
    long long tile = blockIdx.x;
    vf4 r0, r1, r2;
    bool pfull = false;
    if (tile < ntiles) {
        long long gb = tile * 256;
        pfull = ((gb + 256) * 4 <= nrows);
        if (pfull) {
            long long fb = tile * 768 + wbase;
            r0 = x4[fb + lane];
            r1 = x4[fb + lane + 64];
            r2 = x4[fb + lane + 128];
        }
    }

    // build LUT inline (VALU, overlaps the loads above)
    for (int i = tid; i < NLUT; i += 256)
        lut[i] = lut_entry(i & (NBINS - 1), lnw, lnb, w1, b1, w2, b2);
    __syncthreads();                             // the ONLY barrier (LUT ready)

    for (; tile < ntiles; tile += gridDim.x) {
        bool full = pfull;
        // stage current tile: wave-local unit-stride ds_write_b128
        if (full) {
            stage[wbase + lane]       = r0;
            stage[wbase + lane + 64]  = r1;
            stage[wbase + lane + 128] = r2;
        }
        // prefetch next tile (stays in flight across compute: no barriers)
        long long ntile = tile + gridDim.x;
        pfull = false;
        if (ntile < ntiles) {
            long long ngb = ntile * 256;
            pfull = ((ngb + 256) * 4 <= nrows);
            if (pfull) {
                long long fb = ntile * 768 + wbase;
                r0 = x4[fb + lane];
                r1 = x4[fb + lane + 64];
                r2 = x4[fb + lane + 128];
            }
        }
        if (full) {
            // same-wave readback: in-order DS pipe, no barrier needed
            const vf4* my = &stage[wbase + 3 * lane];
            vf4 va = my[0], vb = my[1], vc = my[2];
            vf4 o;
            o.x = row_out(va.x, va.y, va.z, lut);
            o.y = row_out(va.w, vb.x, vb.y, lut);
            o.z = row_out(vb.z, vb.w, vc.x, lut);
            o.w = row_out(vc.y, vc.z, vc.w, lut);
            __builtin_nontemporal_store(o, &out4[tile * 256 + 64 * wave + lane]);
        } else {
            // partial tail tile: direct per-row path
            long long grp  = tile * 256 + 64 * wave + lane;
            long long rbeg = grp * 4;
            for (long long r = rbeg; r < nrows && r < rbeg + 4; ++r)
                out[r] = row_out(x[r*3], x[r*3 + 1], x[r*3 + 2], lut);
        }
    }
}

extern "C" void kernel_launch(void* const* d_in, const int* in_sizes, int n_in,
                              void* d_out, int out_size, void* d_ws, size_t ws_size,
                              hipStream_t stream) {
    const float* x   = (const float*)d_in[0];
    const float* lnw = (const float*)d_in[1];
    const float* lnb = (const float*)d_in[2];
    const float* w1  = (const float*)d_in[3];
    const float* b1  = (const float*)d_in[4];
    const float* w2  = (const float*)d_in[5];
    const float* b2  = (const float*)d_in[6];
    // d_in[7] (log_tau): softmin cancels exactly inside LayerNorm -> unused.
    float* out = (float*)d_out;
    long long nrows = out_size;

    long long T      = (nrows + 3) / 4;          // 4-row groups
    long long ntiles = (T + 255) / 256;          // 12KB tiles
    int grid = (ntiles < 2048) ? (int)ntiles : 2048;

    nn2_fused<<<grid, 256, 0, stream>>>(x, lnw, lnb, w1, b1, w2, b2,
                                        out, nrows, ntiles);
}